// Round 8
// baseline (53.795 us; speedup 1.0000x reference)
//
#include <hip/hip_runtime.h>

#define BATCH 8
#define NROW  2048
#define NF    64
#define CHUNK 64
#define NCH   (NROW / CHUNK)                // 32 chunks, full K per block
#define TOT   ((size_t)BATCH * NROW * NF)   // 1048576

typedef float  f32x4  __attribute__((ext_vector_type(4)));
typedef __bf16 bf16x8 __attribute__((ext_vector_type(8)));
typedef unsigned short u16x8 __attribute__((ext_vector_type(8)));

union frag_cast { u16x8 u; bf16x8 b; };

#define AS1 __attribute__((address_space(1)))
#define AS3 __attribute__((address_space(3)))

__device__ __forceinline__ void gld16f(const float* g, float* l) {
  __builtin_amdgcn_global_load_lds((const AS1 void*)g, (AS3 void*)l, 16, 0, 0);
}
__device__ __forceinline__ void gld16u(const unsigned short* g, unsigned short* l) {
  __builtin_amdgcn_global_load_lds((const AS1 void*)g, (AS3 void*)l, 16, 0, 0);
}
__device__ __forceinline__ float ubits(unsigned u) {
  union { unsigned u; float f; } c; c.u = u; return c.f;
}
__device__ __forceinline__ unsigned fbits(float f) {
  union { float f; unsigned u; } c; c.f = f; return c.u;
}

// ---- pass 1: transpose x, split into 3 bf16 levels: xs[lvl][b][f][j] ----
__global__ __launch_bounds__(256, 4)
void prep_x(const float* __restrict__ xg, unsigned short* __restrict__ xs) {
  __shared__ float t[64][65];
  const int b  = blockIdx.y;
  const int j0 = blockIdx.x * 64;
  const int l  = threadIdx.x & 63;
  const int g  = threadIdx.x >> 6;
  const float* src = xg + ((size_t)b * NROW + j0) * NF;
#pragma unroll
  for (int k = 0; k < 16; ++k) {
    const int j = g * 16 + k;
    t[j][l] = src[(size_t)j * NF + l];
  }
  __syncthreads();
#pragma unroll
  for (int k = 0; k < 16; ++k) {
    const int f = g * 16 + k;
    const float v = t[l][f];
    const unsigned u0 = fbits(v);
    const float f0 = ubits(u0 & 0xFFFF0000u);
    const float r  = v - f0;
    const unsigned u1 = fbits(r);
    const float f1 = ubits(u1 & 0xFFFF0000u);
    const float r2 = r - f1;
    const unsigned u2 = fbits(r2);
    const unsigned short s2 =
        (unsigned short)((u2 + 0x7FFFu + ((u2 >> 16) & 1u)) >> 16);
    const size_t o = ((size_t)b * NF + f) * NROW + j0 + l;
    xs[o]           = (unsigned short)(u0 >> 16);
    xs[o + TOT]     = (unsigned short)(u1 >> 16);
    xs[o + 2 * TOT] = s2;
  }
}

// split 8 f32 -> 3 bf16 fragments (proven r5-r7)
__device__ __forceinline__ void split8(const f32x4 q0, const f32x4 q1,
                                       frag_cast* Af) {
  float av[8];
  *(f32x4*)&av[0] = q0;
  *(f32x4*)&av[4] = q1;
  u16x8 h0, h1, h2;
#pragma unroll
  for (int e = 0; e < 8; ++e) {
    const unsigned u0 = fbits(av[e]);
    const float f0 = ubits(u0 & 0xFFFF0000u);
    const float r  = av[e] - f0;
    const unsigned u1 = fbits(r);
    const float f1 = ubits(u1 & 0xFFFF0000u);
    const float r2 = r - f1;
    const unsigned u2 = fbits(r2);
    h0[e] = (unsigned short)(u0 >> 16);
    h1[e] = (unsigned short)(u1 >> 16);
    h2[e] = (unsigned short)((u2 + 0x7FFFu + ((u2 >> 16) & 1u)) >> 16);
  }
  Af[0].u = h0; Af[1].u = h1; Af[2].u = h2;
}

// ---- pass 2: split-bf16 MFMA GEMM, full-K per block (no partials) ----
// Grid 512 = 64 row-tiles x 8 batches, 2 blocks/CU. Block: 32 rows x 64 cols,
// 4 waves: wave w -> rows (w&1)*16, cols (w>>1)*32 (2 n-tiles).
// LDS/chunk: A 8KB f32 + B 24KB bf16x3, dbuf = 64KB. XOR-swizzle q^(row&7)
// on both (pre-swizzled global source, same XOR on read -> 2 lanes/bank).
// f32 MFMA accum per 32-k sub, f64 fold (r5-proven accuracy). One barrier
// per 64-k chunk; batch<->XCD chunked swizzle keeps xs slice L2-hot.
__global__ __launch_bounds__(256, 4)
void gemm_mfma(const float* __restrict__ ag, const unsigned short* __restrict__ xs,
               float* __restrict__ outg) {
  __shared__ __align__(16) float sA[2][32 * CHUNK];                 // 2 x 8KB
  __shared__ __align__(16) unsigned short sB[2][3 * 64 * CHUNK];    // 2 x 24KB

  const int tid  = threadIdx.x;
  const int ln   = tid & 63;
  const int wv   = tid >> 6;
  const int ln15 = ln & 15;           // A row / B col / D col (within 16-tile)
  const int g    = ln >> 4;           // k-group / D row-group
  const int row8 = ln15 & 7;          // swizzle key (A row & B col share it)
  const int rhalf = wv & 1;           // wave's row half (16 rows)
  const int chalf = wv >> 1;          // wave's col half (32 cols)

  // batch <-> XCD chunked swizzle (nwg=512, 64 blocks per XCD = one batch)
  int flat = blockIdx.x;
  flat = (flat & 7) * 64 + (flat >> 3);
  const int b  = flat >> 6;
  const int bx = flat & 63;
  const int i0 = bx * 32;

  const float* aB = ag + ((size_t)b * NROW + i0) * NROW;
  const unsigned short* xB = xs + (size_t)b * NF * NROW;

  // stage chunk at k-offset j0 into buffer buf (linear LDS dest,
  // inverse-swizzled global source)
  auto stage = [&](int buf, int j0) {
#pragma unroll
    for (int i = 0; i < 2; ++i) {            // A: 512 x 16B slots
      const int s = i * 256 + tid;
      const int r = s >> 4;                  // row 0..31
      const int p = s & 15;                  // quad pos 0..15
      gld16f(aB + (size_t)r * NROW + j0 + ((p ^ (r & 7)) << 2),
             &sA[buf][0] + (i * 256 + wv * 64) * 4);
    }
#pragma unroll
    for (int i = 0; i < 6; ++i) {            // B: 1536 x 16B slots
      const int u   = i * 256 + tid;
      const int lvl = u >> 9;
      const int rem = u & 511;
      const int n   = rem >> 3;              // col 0..63
      const int p   = rem & 7;               // quad pos 0..7
      gld16u(xB + (size_t)lvl * TOT + (size_t)n * NROW + j0 + ((p ^ (n & 7)) << 3),
             &sB[buf][0] + (i * 256 + wv * 64) * 8);
    }
  };

  double macc[2][4];
#pragma unroll
  for (int i = 0; i < 2; ++i)
#pragma unroll
    for (int j = 0; j < 4; ++j) macc[i][j] = 0.0;

  constexpr int AI[6] = {2, 0, 1, 1, 0, 0};
  constexpr int BI[6] = {0, 2, 1, 0, 1, 0};

  const int rowL = rhalf * 16 + ln15;        // local A row 0..31

  stage(0, 0);

#pragma unroll 1
  for (int t = 0; t < NCH; ++t) {
    __syncthreads();                  // drains stage(t); buf^1 free
    if (t + 1 < NCH) stage((t + 1) & 1, (t + 1) * CHUNK);

    const float* sAb = &sA[t & 1][0];
    const unsigned short* sBb = &sB[t & 1][0];

#pragma unroll
    for (int sub = 0; sub < 2; ++sub) {      // two 32-k halves of the chunk
      const int qa0 = (sub * 8 + 2 * g)     ^ row8;   // bit3=sub preserved
      const int qa1 = (sub * 8 + 2 * g + 1) ^ row8;
      const f32x4 q0 = *(const f32x4*)(sAb + rowL * 64 + qa0 * 4);
      const f32x4 q1 = *(const f32x4*)(sAb + rowL * 64 + qa1 * 4);
      frag_cast Af[3];
      split8(q0, q1, Af);

      frag_cast Bv[2][3];
      const int bq = (sub * 4 + g) ^ row8;   // 3-bit quad pos
#pragma unroll
      for (int nt = 0; nt < 2; ++nt) {
        const int nL = chalf * 32 + nt * 16 + ln15;
#pragma unroll
        for (int lvl = 0; lvl < 3; ++lvl)
          Bv[nt][lvl].u = *(const u16x8*)(sBb + lvl * 4096 + nL * 64 + bq * 8);
      }

      f32x4 c[2];
      c[0] = (f32x4){0.f, 0.f, 0.f, 0.f};
      c[1] = (f32x4){0.f, 0.f, 0.f, 0.f};
#pragma unroll
      for (int term = 0; term < 6; ++term)
#pragma unroll
        for (int nt = 0; nt < 2; ++nt)
          c[nt] = __builtin_amdgcn_mfma_f32_16x16x32_bf16(
              Af[AI[term]].b, Bv[nt][BI[term]].b, c[nt], 0, 0, 0);

#pragma unroll
      for (int nt = 0; nt < 2; ++nt) {
        macc[nt][0] += (double)c[nt].x;
        macc[nt][1] += (double)c[nt].y;
        macc[nt][2] += (double)c[nt].z;
        macc[nt][3] += (double)c[nt].w;
      }
    }
  }

  // epilogue: D row = g*4 + r, col = nt*16 + ln15 (verified r5-r7)
#pragma unroll
  for (int nt = 0; nt < 2; ++nt)
#pragma unroll
    for (int r = 0; r < 4; ++r)
      outg[((size_t)b * NROW + i0 + rhalf * 16 + g * 4 + r) * NF +
           chalf * 32 + nt * 16 + ln15] = (macc[nt][r] > 0.5) ? 1.0f : 0.0f;
}

extern "C" void kernel_launch(void* const* d_in, const int* in_sizes, int n_in,
                              void* d_out, int out_size, void* d_ws, size_t ws_size,
                              hipStream_t stream) {
  const float* x = (const float*)d_in[0];
  const float* a = (const float*)d_in[1];
  float* out = (float*)d_out;
  unsigned short* xs = (unsigned short*)d_ws;   // 3*TOT u16 = 6 MB (ws proven >=22MB)

  prep_x<<<dim3(NROW / 64, BATCH), dim3(256), 0, stream>>>(x, xs);
  gemm_mfma<<<dim3(512), dim3(256), 0, stream>>>(a, xs, out);
}

// Round 9
// 53.307 us; speedup vs baseline: 1.0092x; 1.0092x over previous
//
#include <hip/hip_runtime.h>

#define BATCH 8
#define NROW  2048
#define NF    64
#define JSPLIT 4
#define JPB   (NROW / JSPLIT)               // 512 k per block (split path)
#define CHUNK 32
#define TOT   ((size_t)BATCH * NROW * NF)   // 1048576

typedef float  f32x4  __attribute__((ext_vector_type(4)));
typedef float  f32x16 __attribute__((ext_vector_type(16)));
typedef __bf16 bf16x8 __attribute__((ext_vector_type(8)));
typedef unsigned short u16x8 __attribute__((ext_vector_type(8)));

union frag_cast { u16x8 u; bf16x8 b; };

#define AS1 __attribute__((address_space(1)))
#define AS3 __attribute__((address_space(3)))

__device__ __forceinline__ void gld16f(const float* g, float* l) {
  __builtin_amdgcn_global_load_lds((const AS1 void*)g, (AS3 void*)l, 16, 0, 0);
}
__device__ __forceinline__ void gld16u(const unsigned short* g, unsigned short* l) {
  __builtin_amdgcn_global_load_lds((const AS1 void*)g, (AS3 void*)l, 16, 0, 0);
}
__device__ __forceinline__ float ubits(unsigned u) {
  union { unsigned u; float f; } c; c.u = u; return c.f;
}
__device__ __forceinline__ unsigned fbits(float f) {
  union { float f; unsigned u; } c; c.f = f; return c.u;
}

// ---- pass 1: transpose x, split into 3 bf16 levels: xs[lvl][b][f][j] ----
__global__ __launch_bounds__(256, 4)
void prep_x(const float* __restrict__ xg, unsigned short* __restrict__ xs) {
  __shared__ float t[64][65];
  const int b  = blockIdx.y;
  const int j0 = blockIdx.x * 64;
  const int l  = threadIdx.x & 63;
  const int g  = threadIdx.x >> 6;
  const float* src = xg + ((size_t)b * NROW + j0) * NF;
#pragma unroll
  for (int k = 0; k < 16; ++k) {
    const int j = g * 16 + k;
    t[j][l] = src[(size_t)j * NF + l];
  }
  __syncthreads();
#pragma unroll
  for (int k = 0; k < 16; ++k) {
    const int f = g * 16 + k;
    const float v = t[l][f];
    const unsigned u0 = fbits(v);
    const float f0 = ubits(u0 & 0xFFFF0000u);
    const float r  = v - f0;
    const unsigned u1 = fbits(r);
    const float f1 = ubits(u1 & 0xFFFF0000u);
    const float r2 = r - f1;
    const unsigned u2 = fbits(r2);
    const unsigned short s2 =
        (unsigned short)((u2 + 0x7FFFu + ((u2 >> 16) & 1u)) >> 16);
    const size_t o = ((size_t)b * NF + f) * NROW + j0 + l;
    xs[o]           = (unsigned short)(u0 >> 16);
    xs[o + TOT]     = (unsigned short)(u1 >> 16);
    xs[o + 2 * TOT] = s2;
  }
}

// split 8 f32 -> 3 bf16 fragments (proven r5-r8)
__device__ __forceinline__ void split8(const f32x4 q0, const f32x4 q1,
                                       frag_cast* Af) {
  float av[8];
  *(f32x4*)&av[0] = q0;
  *(f32x4*)&av[4] = q1;
  u16x8 h0, h1, h2;
#pragma unroll
  for (int e = 0; e < 8; ++e) {
    const unsigned u0 = fbits(av[e]);
    const float f0 = ubits(u0 & 0xFFFF0000u);
    const float r  = av[e] - f0;
    const unsigned u1 = fbits(r);
    const float f1 = ubits(u1 & 0xFFFF0000u);
    const float r2 = r - f1;
    const unsigned u2 = fbits(r2);
    h0[e] = (unsigned short)(u0 >> 16);
    h1[e] = (unsigned short)(u1 >> 16);
    h2[e] = (unsigned short)((u2 + 0x7FFFu + ((u2 >> 16) & 1u)) >> 16);
  }
  Af[0].u = h0; Af[1].u = h1; Af[2].u = h2;
}

// ---- pass 2: split-bf16 32x32x16 MFMA GEMM (r7 staging skeleton) ----
// Grid 1024 (1-D), 4 blocks/CU. Block: 64 rows x 64 cols x K=512; 4 waves
// 2x2, each wave one 32x32 tile via v_mfma_f32_32x32x16_bf16.
// LDS/chunk: A 8KB f32 + B 12KB bf16x3lvl, dbuf = 40KB; XOR-swizzled via
// pre-swizzled global source (linear gld_lds dest). b = flat&7 -> each XCD
// owns one batch (768KB xs slice L2-resident). f64 fold per 32-k chunk.
template <bool DIRECT>
__global__ __launch_bounds__(256, 4)
void gemm_mfma(const float* __restrict__ ag, const unsigned short* __restrict__ xs,
               float* __restrict__ outg, float* __restrict__ wp) {
  __shared__ __align__(16) float sA[2][64 * CHUNK];                 // 2 x 8KB
  __shared__ __align__(16) unsigned short sB[2][3 * 64 * CHUNK];    // 2 x 12KB

  const int tid   = threadIdx.x;
  const int ln    = tid & 63;
  const int wv    = tid >> 6;
  const int l31   = ln & 31;
  const int h     = ln >> 5;          // k-half selector (A/B frags)
  const int rhalf = wv & 1;           // wave row half
  const int chalf = wv >> 1;          // wave col half

  // batch <-> XCD: dispatch round-robins XCD by flat&7 -> give each XCD one b
  const int flat = blockIdx.x;
  const int b    = flat & 7;
  const int bx   = (flat >> 3) & 31;
  const int z    = DIRECT ? 0 : (flat >> 8);
  const int i0   = bx * 64;
  const int jb   = z * JPB;
  const int nch  = (DIRECT ? NROW : JPB) / CHUNK;   // 64 or 16

  const float* aB = ag + ((size_t)b * NROW + i0) * NROW;
  const unsigned short* xB = xs + (size_t)b * NF * NROW;

  // stage chunk at k-offset j0 (linear LDS dest, inverse-swizzled source)
  auto stage = [&](int buf, int j0) {
#pragma unroll
    for (int i = 0; i < 2; ++i) {            // A: 512 x 16B slots
      const int s   = i * 256 + tid;
      const int row = s >> 3;
      const int q   = (s & 7) ^ (row & 7);
      gld16f(aB + (size_t)row * NROW + j0 + q * 4,
             &sA[buf][0] + (i * 256 + wv * 64) * 4);
    }
#pragma unroll
    for (int lvl = 0; lvl < 3; ++lvl) {      // B: 3 x 256 x 16B slots
      const int n = tid >> 2;
      const int q = (tid & 3) ^ ((n >> 1) & 3);
      gld16u(xB + (size_t)lvl * TOT + (size_t)n * NROW + j0 + q * 8,
             &sB[buf][0] + (lvl * 256 + wv * 64) * 8);
    }
  };

  double macc[16];
#pragma unroll
  for (int i = 0; i < 16; ++i) macc[i] = 0.0;

  constexpr int AI[6] = {2, 0, 1, 1, 0, 0};
  constexpr int BI[6] = {0, 2, 1, 0, 1, 0};

  const int arow = rhalf * 32 + l31;   // A row 0..63
  const int akey = l31 & 7;            // == arow & 7
  const int ncol = chalf * 32 + l31;   // B col 0..63
  const int bkey = (l31 >> 1) & 3;     // == (ncol>>1)&3

  stage(0, jb);

#pragma unroll 1
  for (int t = 0; t < nch; ++t) {
    __syncthreads();                  // drains stage(t); buf^1 free
    if (t + 1 < nch) stage((t + 1) & 1, jb + (t + 1) * CHUNK);

    const float* sAb = &sA[t & 1][0];
    const unsigned short* sBb = &sB[t & 1][0];

    f32x16 c;
#pragma unroll
    for (int i = 0; i < 16; ++i) c[i] = 0.f;

#pragma unroll
    for (int sub = 0; sub < 2; ++sub) {      // two 16-k halves of the chunk
      // A frag: lane = row arow, k = sub*16 + h*8 .. +8  (quads 4sub+2h, +1)
      const int p0 = (4 * sub + 2 * h)     ^ akey;
      const int p1 = (4 * sub + 2 * h + 1) ^ akey;
      const f32x4 q0 = *(const f32x4*)(sAb + arow * 32 + p0 * 4);
      const f32x4 q1 = *(const f32x4*)(sAb + arow * 32 + p1 * 4);
      frag_cast Af[3];
      split8(q0, q1, Af);

      // B frags: lane = col ncol, same k-span  (octet 2sub+h)
      const int bq = (2 * sub + h) ^ bkey;
      frag_cast Bv[3];
#pragma unroll
      for (int lvl = 0; lvl < 3; ++lvl)
        Bv[lvl].u = *(const u16x8*)(sBb + lvl * 2048 + ncol * 32 + bq * 8);

#pragma unroll
      for (int term = 0; term < 6; ++term)
        c = __builtin_amdgcn_mfma_f32_32x32x16_bf16(
            Af[AI[term]].b, Bv[BI[term]].b, c, 0, 0, 0);
    }
#pragma unroll
    for (int i = 0; i < 16; ++i) macc[i] += (double)c[i];
  }

  // epilogue: D row = (reg&3) + 8*(reg>>2) + 4*h, col = l31 (m74/m101 layout)
  if (DIRECT) {
#pragma unroll
    for (int reg = 0; reg < 16; ++reg) {
      const int row = i0 + rhalf * 32 + (reg & 3) + 8 * (reg >> 2) + 4 * h;
      outg[((size_t)b * NROW + row) * NF + chalf * 32 + l31] =
          (macc[reg] > 0.5) ? 1.0f : 0.0f;
    }
  } else {
    float* wb = wp + (size_t)z * TOT;
#pragma unroll
    for (int reg = 0; reg < 16; ++reg) {
      const int row = i0 + rhalf * 32 + (reg & 3) + 8 * (reg >> 2) + 4 * h;
      wb[((size_t)b * NROW + row) * NF + chalf * 32 + l31] = (float)macc[reg];
    }
  }
}

// ---- pass 3: reduce JSPLIT partials in f64, threshold ----
__global__ __launch_bounds__(256)
void combine_thresh(const float* __restrict__ wsv, float* __restrict__ outg) {
  const size_t e = ((size_t)blockIdx.x * 256 + threadIdx.x) * 4;
  f32x4 p0 = *(const f32x4*)(wsv + e);
  f32x4 p1 = *(const f32x4*)(wsv + e + TOT);
  f32x4 p2 = *(const f32x4*)(wsv + e + 2 * TOT);
  f32x4 p3 = *(const f32x4*)(wsv + e + 3 * TOT);
  f32x4 o;
  o.x = (((double)p0.x + p1.x + p2.x + p3.x) > 0.5) ? 1.0f : 0.0f;
  o.y = (((double)p0.y + p1.y + p2.y + p3.y) > 0.5) ? 1.0f : 0.0f;
  o.z = (((double)p0.z + p1.z + p2.z + p3.z) > 0.5) ? 1.0f : 0.0f;
  o.w = (((double)p0.w + p1.w + p2.w + p3.w) > 0.5) ? 1.0f : 0.0f;
  *(f32x4*)(outg + e) = o;
}

extern "C" void kernel_launch(void* const* d_in, const int* in_sizes, int n_in,
                              void* d_out, int out_size, void* d_ws, size_t ws_size,
                              hipStream_t stream) {
  const float* x = (const float*)d_in[0];
  const float* a = (const float*)d_in[1];
  float* out = (float*)d_out;
  unsigned short* xs = (unsigned short*)d_ws;                 // 6 MB
  float* wp = (float*)((char*)d_ws + 3 * TOT * sizeof(unsigned short));

  prep_x<<<dim3(NROW / 64, BATCH), dim3(256), 0, stream>>>(x, xs);

  const size_t need = 3 * TOT * sizeof(unsigned short)
                    + (size_t)JSPLIT * TOT * sizeof(float);   // 22 MB
  if (ws_size >= need) {
    gemm_mfma<false><<<dim3(JSPLIT * BATCH * (NROW / 64)), dim3(256), 0, stream>>>(
        a, xs, out, wp);
    combine_thresh<<<dim3((unsigned)(TOT / 1024)), dim3(256), 0, stream>>>(wp, out);
  } else {
    gemm_mfma<true><<<dim3(BATCH * (NROW / 64)), dim3(256), 0, stream>>>(
        a, xs, out, nullptr);
  }
}